// Round 28
// baseline (155.117 us; speedup 1.0000x reference)
//
#include <hip/hip_runtime.h>
#include <hip/hip_bf16.h>

#define N_NODES 8192
#define E_EDGES 262144
#define HID 128
#define FIN 256
#define CAP 128  // CSR bin capacity per node; deg ~ Binom(262144,1/8192), max ~60
#define NB 64    // histogram edge-blocks (4096 edges each)

typedef __attribute__((ext_vector_type(8))) short bf16x8;
typedef __attribute__((ext_vector_type(4))) float f32x4;

// ---- FUSED: count_hist (blocks 0..63) + xw (blocks 64..191), 1024 thr.
// Independent phases — count reads dst, xw reads x/W; no shared state, no
// ordering requirement. Co-schedules on the CUs instead of serializing
// across a kernel boundary (saves 1 drain + overlaps xw under count). ----
__global__ __launch_bounds__(1024) void count_xw(const int* __restrict__ dst,
                                                 unsigned short* __restrict__ histG,
                                                 const float* __restrict__ x,
                                                 const float* __restrict__ W,
                                                 float* __restrict__ h) {
    __shared__ unsigned hist[N_NODES];  // 32 KB (count blocks only)
    int bid = blockIdx.x;
    if (bid < NB) {
        // ---- per-block LDS histogram of dst; LDS atomics only ----
#pragma unroll
        for (int i = 0; i < 8; ++i) hist[i * 1024 + threadIdx.x] = 0u;
        __syncthreads();
        int gid = bid * 1024 + threadIdx.x;
        int4 d4 = ((const int4*)dst)[gid];  // 4 edges/thread, coalesced
        atomicAdd(&hist[d4.x], 1u);
        atomicAdd(&hist[d4.y], 1u);
        atomicAdd(&hist[d4.z], 1u);
        atomicAdd(&hist[d4.w], 1u);
        __syncthreads();
        size_t base = (size_t)bid * N_NODES;
#pragma unroll
        for (int i = 0; i < 8; ++i) {
            int d = i * 1024 + threadIdx.x;
            histG[base + d] = (unsigned short)hist[d];  // coalesced u16 stores
        }
        return;
    }
    // ---- xw: h = X @ W, 64 rows/block (128 blocks) ----
    int b2 = bid - NB;
    int col = threadIdx.x & 127;
    int row0 = b2 * 64 + (threadIdx.x >> 7) * 8;  // 8 groups x 8 rows
    const float* xr = x + (size_t)row0 * FIN;
    float acc[8];
#pragma unroll
    for (int r = 0; r < 8; ++r) acc[r] = 0.f;

    for (int k = 0; k < FIN; k += 4) {
        float4 xv[8];
#pragma unroll
        for (int r = 0; r < 8; ++r) xv[r] = *(const float4*)(xr + r * FIN + k);
#pragma unroll
        for (int kk = 0; kk < 4; ++kk) {
            float w = W[(size_t)(k + kk) * HID + col];
#pragma unroll
            for (int r = 0; r < 8; ++r)
                acc[r] = fmaf(((const float*)&xv[r])[kk], w, acc[r]);
        }
    }
#pragma unroll
    for (int r = 0; r < 8; ++r)
        h[(size_t)(row0 + r) * HID + col] = acc[r];
}

// ---- K2: exclusive prefix over the 64 blocks, per node; batched reg-scan. ----
__global__ __launch_bounds__(256) void scan_hist(unsigned short* __restrict__ histG,
                                                 unsigned* __restrict__ deg) {
    int d = blockIdx.x * 256 + threadIdx.x;  // 32 blocks x 256 = 8192
    unsigned v[NB];
#pragma unroll
    for (int b = 0; b < NB; ++b) v[b] = histG[(size_t)b * N_NODES + d];  // independent
    unsigned run = 0;
#pragma unroll
    for (int b = 0; b < NB; ++b) {
        unsigned t = v[b];
        v[b] = run;  // exclusive prefix
        run += t;
    }
#pragma unroll
    for (int b = 0; b < NB; ++b)
        histG[(size_t)b * N_NODES + d] = (unsigned short)v[b];  // independent
    deg[d] = run;
}

// ---- K3: placement. Local rank via LDS atomic + per-(block,node) base. ----
__global__ __launch_bounds__(1024) void place_csr(const int* __restrict__ src,
                                                  const int* __restrict__ dst,
                                                  const unsigned short* __restrict__ histG,
                                                  int* __restrict__ csr) {
    __shared__ unsigned lcur[N_NODES];  // 32 KB
#pragma unroll
    for (int i = 0; i < 8; ++i) lcur[i * 1024 + threadIdx.x] = 0u;
    __syncthreads();
    int gid = blockIdx.x * 1024 + threadIdx.x;
    int4 s4 = ((const int4*)src)[gid];
    int4 d4 = ((const int4*)dst)[gid];
    size_t base = (size_t)blockIdx.x * N_NODES;
    int ds[4] = {d4.x, d4.y, d4.z, d4.w};
    int ss[4] = {s4.x, s4.y, s4.z, s4.w};
#pragma unroll
    for (int j = 0; j < 4; ++j) {
        int d = ds[j];
        unsigned lpos = atomicAdd(&lcur[d], 1u);  // LDS atomic
        unsigned gbase = histG[base + d];         // own block's region, L2-hot
        csr[(size_t)d * CAP + gbase + lpos] = ss[j];
    }
}

// ---- sym-normalized aggregation + bias + relu (r15 ILP form). ----
__global__ __launch_bounds__(256) void agg_kernel(const float* __restrict__ h,
                                                  const unsigned* __restrict__ cnt,
                                                  const int* __restrict__ csr_src,
                                                  const float* __restrict__ b,
                                                  float* __restrict__ z_out,
                                                  __hip_bfloat16* __restrict__ zb) {
    int row = blockIdx.x;
    int slot = threadIdx.x >> 6;  // 0..3 (wave id)
    int fp = threadIdx.x & 63;    // feature pair index
    const float2* h2 = (const float2*)h;
    const int* bin = csr_src + (size_t)row * CAP;

    unsigned ne = cnt[row];
    float ax = 0.f, ay = 0.f;
    for (unsigned base = (unsigned)slot * 8; base < ne; base += 32) {
        int4 i0 = *(const int4*)(bin + base);
        int4 i1 = *(const int4*)(bin + base + 4);
        int ss[8] = {i0.x, i0.y, i0.z, i0.w, i1.x, i1.y, i1.z, i1.w};
        unsigned rem = ne - base;  // >= 1
#pragma unroll
        for (int j = 0; j < 8; ++j) {
            int s = ((unsigned)j < rem) ? ss[j] : ss[0];  // clamp: always valid
            float ds = rsqrtf((float)(cnt[s] + 1u));
            ds = ((unsigned)j < rem) ? ds : 0.f;          // tail contributes 0
            float2 hv = h2[(size_t)s * 64 + fp];          // independent loads
            ax = fmaf(hv.x, ds, ax);
            ay = fmaf(hv.y, ds, ay);
        }
    }
    __shared__ float part[4][64][2];
    part[slot][fp][0] = ax;
    part[slot][fp][1] = ay;
    __syncthreads();
    if (slot == 0) {
        float di = rsqrtf((float)(ne + 1u));
        float2 hv = h2[(size_t)row * 64 + fp];
        float sx = (part[0][fp][0] + part[1][fp][0]) + (part[2][fp][0] + part[3][fp][0]) + hv.x * di;
        float sy = (part[0][fp][1] + part[1][fp][1]) + (part[2][fp][1] + part[3][fp][1]) + hv.y * di;
        float2 bb = ((const float2*)b)[fp];
        float zx = fmaxf(fmaf(sx, di, bb.x), 0.f);
        float zy = fmaxf(fmaf(sy, di, bb.y), 0.f);
        ((float2*)z_out)[(size_t)row * 64 + fp] = make_float2(zx, zy);
        unsigned short bx = __builtin_bit_cast(unsigned short, __float2bfloat16(zx));
        unsigned short by = __builtin_bit_cast(unsigned short, __float2bfloat16(zy));
        ((unsigned*)zb)[(size_t)row * 64 + fp] = ((unsigned)by << 16) | (unsigned)bx;
    }
}

// ---- adj = sigmoid(z @ z^T): r25 EXACT (4 waves/SIMD occupancy optimum).
// Triangle at 512x512 super-tiles; per-wave 64x64 (acc[4][4] ~116 VGPR).
// Block = 4 waves as 1x4 = 64 rows x 256 cols; 136 pairs x 8 strips x
// 2 col-windows = 2176 blocks. Primary 1KB runs; mirror nt float4. ----
__global__ __launch_bounds__(256) void gemm_sig(const __hip_bfloat16* __restrict__ zb,
                                                float* __restrict__ adj) {
    int sub = blockIdx.x & 15;
    int strip = sub & 7;   // row strip (64 rows)
    int cw = sub >> 3;     // col window (256 cols)
    int p = blockIdx.x >> 4;  // 0..135 triangular pair index
    int TI = 0, rem = p;
    while (rem >= 16 - TI) { rem -= 16 - TI; ++TI; }
    int TJ = TI + rem;

    int wid = threadIdx.x >> 6;  // 0..3: col sub-window (64 cols each)
    int lane = threadIdx.x & 63;
    int lr = lane & 15;  // fragment index
    int hi = lane >> 4;  // 0..3
    int lk = hi * 8;     // k sub-offset

    int row0 = TI * 512 + strip * 64;             // adj rows (A = z rows)
    int col0 = TJ * 512 + cw * 256 + wid * 64;    // adj cols (B = z rows)

    f32x4 acc[4][4];
#pragma unroll
    for (int m = 0; m < 4; ++m)
#pragma unroll
        for (int n = 0; n < 4; ++n) acc[m][n] = (f32x4){0.f, 0.f, 0.f, 0.f};

#pragma unroll
    for (int ks = 0; ks < 4; ++ks) {
        int k = ks * 32 + lk;
        bf16x8 a[4], bfr[4];
#pragma unroll
        for (int m = 0; m < 4; ++m)
            a[m] = *(const bf16x8*)(zb + (size_t)(row0 + m * 16 + lr) * HID + k);
#pragma unroll
        for (int n = 0; n < 4; ++n)
            bfr[n] = *(const bf16x8*)(zb + (size_t)(col0 + n * 16 + lr) * HID + k);
#pragma unroll
        for (int m = 0; m < 4; ++m)
#pragma unroll
            for (int n = 0; n < 4; ++n)
                acc[m][n] = __builtin_amdgcn_mfma_f32_16x16x32_bf16(a[m], bfr[n], acc[m][n], 0, 0, 0);
    }

    int orow = hi * 4;
    bool mirror = (TI != TJ);
#pragma unroll
    for (int m = 0; m < 4; ++m) {
        int rowb = row0 + m * 16 + orow;  // multiple of 4
#pragma unroll
        for (int n = 0; n < 4; ++n) {
            int col = col0 + n * 16 + lr;
            f32x4 s4;
#pragma unroll
            for (int r = 0; r < 4; ++r) {
                float v = acc[m][n][r];
                s4[r] = __builtin_amdgcn_rcpf(1.0f + __expf(-v));
            }
            // primary row-major: wave covers 4 rows x 16 consecutive cols
            // per instr = 4 full 64B lines; 1KB runs per adj-row per block.
#pragma unroll
            for (int r = 0; r < 4; ++r)
                adj[(size_t)(rowb + r) * N_NODES + col] = s4[r];
            // mirror: float4 full-line nt stores at adj[col][row].
            if (mirror)
                __builtin_nontemporal_store(s4, (f32x4*)(adj + (size_t)col * N_NODES + rowb));
        }
    }
}

extern "C" void kernel_launch(void* const* d_in, const int* in_sizes, int n_in,
                              void* d_out, int out_size, void* d_ws, size_t ws_size,
                              hipStream_t stream) {
    const float* x = (const float*)d_in[0];
    const int* ei = (const int*)d_in[1];
    const float* W = (const float*)d_in[2];
    const float* b = (const float*)d_in[3];
    const int* src = ei;
    const int* dst = ei + E_EDGES;

    float* adj = (float*)d_out;
    float* z_out = (float*)d_out + (size_t)N_NODES * N_NODES;

    char* ws = (char*)d_ws;
    float* h = (float*)ws;                                        // 4 MB
    __hip_bfloat16* zb = (__hip_bfloat16*)(ws + (4u << 20));      // 2 MB
    unsigned short* histG = (unsigned short*)(ws + (6u << 20));   // 1 MB (64 x 8192 u16)
    unsigned* deg = (unsigned*)(ws + (7u << 20));                 // 32 KB
    int* csr = (int*)(ws + (7u << 20) + (32u << 10));             // 4 MB (8192*128*4)

    // fused count+xw (independent phases, co-scheduled, 1 fewer boundary)
    hipLaunchKernelGGL(count_xw, dim3(NB + 128), dim3(1024), 0, stream, dst, histG, x, W, h);
    hipLaunchKernelGGL(scan_hist, dim3(32), dim3(256), 0, stream, histG, deg);
    hipLaunchKernelGGL(place_csr, dim3(NB), dim3(1024), 0, stream, src, dst, histG, csr);
    hipLaunchKernelGGL(agg_kernel, dim3(N_NODES), dim3(256), 0, stream, h, deg, csr, b, z_out, zb);
    hipLaunchKernelGGL(gemm_sig, dim3(136 * 16), dim3(256), 0, stream, zb, adj);
}

// Round 29
// 124.497 us; speedup vs baseline: 1.2460x; 1.2460x over previous
//
#include <hip/hip_runtime.h>
#include <hip/hip_bf16.h>

#define N_NODES 8192
#define E_EDGES 262144
#define HID 128
#define FIN 256
#define CAP 128  // CSR bin capacity per node; deg ~ Binom(262144,1/8192), max ~60
#define NB 64    // histogram edge-blocks (4096 edges each)

typedef __attribute__((ext_vector_type(8))) short bf16x8;
typedef __attribute__((ext_vector_type(4))) float f32x4;

// ---- h = X @ W (fp32 vector). 16 rows/block. ----
__global__ __launch_bounds__(256) void xw_kernel(const float* __restrict__ x,
                                                 const float* __restrict__ W,
                                                 float* __restrict__ h) {
    int col = threadIdx.x & 127;
    int row0 = blockIdx.x * 16 + (threadIdx.x >> 7) * 8;
    const float* xr = x + (size_t)row0 * FIN;
    float acc[8];
#pragma unroll
    for (int r = 0; r < 8; ++r) acc[r] = 0.f;

    for (int k = 0; k < FIN; k += 4) {
        float4 xv[8];
#pragma unroll
        for (int r = 0; r < 8; ++r) xv[r] = *(const float4*)(xr + r * FIN + k);
#pragma unroll
        for (int kk = 0; kk < 4; ++kk) {
            float w = W[(size_t)(k + kk) * HID + col];
#pragma unroll
            for (int r = 0; r < 8; ++r)
                acc[r] = fmaf(((const float*)&xv[r])[kk], w, acc[r]);
        }
    }
#pragma unroll
    for (int r = 0; r < 8; ++r)
        h[(size_t)(row0 + r) * HID + col] = acc[r];
}

// ---- K1: per-block LDS histogram of dst. 64 blocks x 1024 thr x 4 edges. ----
__global__ __launch_bounds__(1024) void count_hist(const int* __restrict__ dst,
                                                   unsigned short* __restrict__ histG) {
    __shared__ unsigned hist[N_NODES];  // 32 KB
#pragma unroll
    for (int i = 0; i < 8; ++i) hist[i * 1024 + threadIdx.x] = 0u;
    __syncthreads();
    int gid = blockIdx.x * 1024 + threadIdx.x;
    int4 d4 = ((const int4*)dst)[gid];  // 4 edges/thread, coalesced
    atomicAdd(&hist[d4.x], 1u);
    atomicAdd(&hist[d4.y], 1u);
    atomicAdd(&hist[d4.z], 1u);
    atomicAdd(&hist[d4.w], 1u);
    __syncthreads();
    size_t base = (size_t)blockIdx.x * N_NODES;
#pragma unroll
    for (int i = 0; i < 8; ++i) {
        int d = i * 1024 + threadIdx.x;
        histG[base + d] = (unsigned short)hist[d];  // coalesced u16 stores
    }
}

// ---- K2: exclusive prefix over the 64 blocks, per node; batched reg-scan. ----
__global__ __launch_bounds__(256) void scan_hist(unsigned short* __restrict__ histG,
                                                 unsigned* __restrict__ deg) {
    int d = blockIdx.x * 256 + threadIdx.x;  // 32 blocks x 256 = 8192
    unsigned v[NB];
#pragma unroll
    for (int b = 0; b < NB; ++b) v[b] = histG[(size_t)b * N_NODES + d];  // independent
    unsigned run = 0;
#pragma unroll
    for (int b = 0; b < NB; ++b) {
        unsigned t = v[b];
        v[b] = run;  // exclusive prefix
        run += t;
    }
#pragma unroll
    for (int b = 0; b < NB; ++b)
        histG[(size_t)b * N_NODES + d] = (unsigned short)v[b];  // independent
    deg[d] = run;
}

// ---- K3: placement. Local rank via LDS atomic + per-(block,node) base. ----
__global__ __launch_bounds__(1024) void place_csr(const int* __restrict__ src,
                                                  const int* __restrict__ dst,
                                                  const unsigned short* __restrict__ histG,
                                                  int* __restrict__ csr) {
    __shared__ unsigned lcur[N_NODES];  // 32 KB
#pragma unroll
    for (int i = 0; i < 8; ++i) lcur[i * 1024 + threadIdx.x] = 0u;
    __syncthreads();
    int gid = blockIdx.x * 1024 + threadIdx.x;
    int4 s4 = ((const int4*)src)[gid];
    int4 d4 = ((const int4*)dst)[gid];
    size_t base = (size_t)blockIdx.x * N_NODES;
    int ds[4] = {d4.x, d4.y, d4.z, d4.w};
    int ss[4] = {s4.x, s4.y, s4.z, s4.w};
#pragma unroll
    for (int j = 0; j < 4; ++j) {
        int d = ds[j];
        unsigned lpos = atomicAdd(&lcur[d], 1u);  // LDS atomic
        unsigned gbase = histG[base + d];         // own block's region, L2-hot
        csr[(size_t)d * CAP + gbase + lpos] = ss[j];
    }
}

// ---- sym-normalized aggregation + bias + relu (r15 ILP form). ----
__global__ __launch_bounds__(256) void agg_kernel(const float* __restrict__ h,
                                                  const unsigned* __restrict__ cnt,
                                                  const int* __restrict__ csr_src,
                                                  const float* __restrict__ b,
                                                  float* __restrict__ z_out,
                                                  __hip_bfloat16* __restrict__ zb) {
    int row = blockIdx.x;
    int slot = threadIdx.x >> 6;  // 0..3 (wave id)
    int fp = threadIdx.x & 63;    // feature pair index
    const float2* h2 = (const float2*)h;
    const int* bin = csr_src + (size_t)row * CAP;

    unsigned ne = cnt[row];
    float ax = 0.f, ay = 0.f;
    for (unsigned base = (unsigned)slot * 8; base < ne; base += 32) {
        int4 i0 = *(const int4*)(bin + base);
        int4 i1 = *(const int4*)(bin + base + 4);
        int ss[8] = {i0.x, i0.y, i0.z, i0.w, i1.x, i1.y, i1.z, i1.w};
        unsigned rem = ne - base;  // >= 1
#pragma unroll
        for (int j = 0; j < 8; ++j) {
            int s = ((unsigned)j < rem) ? ss[j] : ss[0];  // clamp: always valid
            float ds = rsqrtf((float)(cnt[s] + 1u));
            ds = ((unsigned)j < rem) ? ds : 0.f;          // tail contributes 0
            float2 hv = h2[(size_t)s * 64 + fp];          // independent loads
            ax = fmaf(hv.x, ds, ax);
            ay = fmaf(hv.y, ds, ay);
        }
    }
    __shared__ float part[4][64][2];
    part[slot][fp][0] = ax;
    part[slot][fp][1] = ay;
    __syncthreads();
    if (slot == 0) {
        float di = rsqrtf((float)(ne + 1u));
        float2 hv = h2[(size_t)row * 64 + fp];
        float sx = (part[0][fp][0] + part[1][fp][0]) + (part[2][fp][0] + part[3][fp][0]) + hv.x * di;
        float sy = (part[0][fp][1] + part[1][fp][1]) + (part[2][fp][1] + part[3][fp][1]) + hv.y * di;
        float2 bb = ((const float2*)b)[fp];
        float zx = fmaxf(fmaf(sx, di, bb.x), 0.f);
        float zy = fmaxf(fmaf(sy, di, bb.y), 0.f);
        ((float2*)z_out)[(size_t)row * 64 + fp] = make_float2(zx, zy);
        unsigned short bx = __builtin_bit_cast(unsigned short, __float2bfloat16(zx));
        unsigned short by = __builtin_bit_cast(unsigned short, __float2bfloat16(zy));
        ((unsigned*)zb)[(size_t)row * 64 + fp] = ((unsigned)by << 16) | (unsigned)bx;
    }
}

// ---- adj = sigmoid(z @ z^T): r25 EXACT (4 waves/SIMD occupancy optimum).
// Triangle at 512x512 super-tiles; per-wave 64x64 (acc[4][4] ~116 VGPR).
// Block = 4 waves as 1x4 = 64 rows x 256 cols; 136 pairs x 8 strips x
// 2 col-windows = 2176 blocks. Primary 1KB runs; mirror nt float4. ----
__global__ __launch_bounds__(256) void gemm_sig(const __hip_bfloat16* __restrict__ zb,
                                                float* __restrict__ adj) {
    int sub = blockIdx.x & 15;
    int strip = sub & 7;   // row strip (64 rows)
    int cw = sub >> 3;     // col window (256 cols)
    int p = blockIdx.x >> 4;  // 0..135 triangular pair index
    int TI = 0, rem = p;
    while (rem >= 16 - TI) { rem -= 16 - TI; ++TI; }
    int TJ = TI + rem;

    int wid = threadIdx.x >> 6;  // 0..3: col sub-window (64 cols each)
    int lane = threadIdx.x & 63;
    int lr = lane & 15;  // fragment index
    int hi = lane >> 4;  // 0..3
    int lk = hi * 8;     // k sub-offset

    int row0 = TI * 512 + strip * 64;             // adj rows (A = z rows)
    int col0 = TJ * 512 + cw * 256 + wid * 64;    // adj cols (B = z rows)

    f32x4 acc[4][4];
#pragma unroll
    for (int m = 0; m < 4; ++m)
#pragma unroll
        for (int n = 0; n < 4; ++n) acc[m][n] = (f32x4){0.f, 0.f, 0.f, 0.f};

#pragma unroll
    for (int ks = 0; ks < 4; ++ks) {
        int k = ks * 32 + lk;
        bf16x8 a[4], bfr[4];
#pragma unroll
        for (int m = 0; m < 4; ++m)
            a[m] = *(const bf16x8*)(zb + (size_t)(row0 + m * 16 + lr) * HID + k);
#pragma unroll
        for (int n = 0; n < 4; ++n)
            bfr[n] = *(const bf16x8*)(zb + (size_t)(col0 + n * 16 + lr) * HID + k);
#pragma unroll
        for (int m = 0; m < 4; ++m)
#pragma unroll
            for (int n = 0; n < 4; ++n)
                acc[m][n] = __builtin_amdgcn_mfma_f32_16x16x32_bf16(a[m], bfr[n], acc[m][n], 0, 0, 0);
    }

    int orow = hi * 4;
    bool mirror = (TI != TJ);
#pragma unroll
    for (int m = 0; m < 4; ++m) {
        int rowb = row0 + m * 16 + orow;  // multiple of 4
#pragma unroll
        for (int n = 0; n < 4; ++n) {
            int col = col0 + n * 16 + lr;
            f32x4 s4;
#pragma unroll
            for (int r = 0; r < 4; ++r) {
                float v = acc[m][n][r];
                s4[r] = __builtin_amdgcn_rcpf(1.0f + __expf(-v));
            }
            // primary row-major: wave covers 4 rows x 16 consecutive cols
            // per instr = 4 full 64B lines; 1KB runs per adj-row per block.
#pragma unroll
            for (int r = 0; r < 4; ++r)
                adj[(size_t)(rowb + r) * N_NODES + col] = s4[r];
            // mirror: float4 full-line nt stores at adj[col][row].
            if (mirror)
                __builtin_nontemporal_store(s4, (f32x4*)(adj + (size_t)col * N_NODES + rowb));
        }
    }
}

extern "C" void kernel_launch(void* const* d_in, const int* in_sizes, int n_in,
                              void* d_out, int out_size, void* d_ws, size_t ws_size,
                              hipStream_t stream) {
    const float* x = (const float*)d_in[0];
    const int* ei = (const int*)d_in[1];
    const float* W = (const float*)d_in[2];
    const float* b = (const float*)d_in[3];
    const int* src = ei;
    const int* dst = ei + E_EDGES;

    float* adj = (float*)d_out;
    float* z_out = (float*)d_out + (size_t)N_NODES * N_NODES;

    char* ws = (char*)d_ws;
    float* h = (float*)ws;                                        // 4 MB
    __hip_bfloat16* zb = (__hip_bfloat16*)(ws + (4u << 20));      // 2 MB
    unsigned short* histG = (unsigned short*)(ws + (6u << 20));   // 1 MB (64 x 8192 u16)
    unsigned* deg = (unsigned*)(ws + (7u << 20));                 // 32 KB
    int* csr = (int*)(ws + (7u << 20) + (32u << 10));             // 4 MB (8192*128*4)

    hipLaunchKernelGGL(xw_kernel, dim3(N_NODES / 16), dim3(256), 0, stream, x, W, h);
    hipLaunchKernelGGL(count_hist, dim3(NB), dim3(1024), 0, stream, dst, histG);
    hipLaunchKernelGGL(scan_hist, dim3(32), dim3(256), 0, stream, histG, deg);
    hipLaunchKernelGGL(place_csr, dim3(NB), dim3(1024), 0, stream, src, dst, histG, csr);
    hipLaunchKernelGGL(agg_kernel, dim3(N_NODES), dim3(256), 0, stream, h, deg, csr, b, z_out, zb);
    hipLaunchKernelGGL(gemm_sig, dim3(136 * 16), dim3(256), 0, stream, zb, adj);
}